// Round 2
// baseline (1148.914 us; speedup 1.0000x reference)
//
#include <hip/hip_runtime.h>

// Problem constants (from setup_inputs): B=2, G=512, N=4096, C=768, k=4
#define BATCH 2
#define GCOARSE 512
#define NQ 4096
#define CIN 768
#define C1 512   // stage-1 out channels
#define C2 768   // stage-2 out channels

// ---------------------------------------------------------------------------
// KNN: per query keep 4 smallest d = (qq + rr) - 2*dot (reference formula),
// ties keep lower index (matches stable top_k).
// ---------------------------------------------------------------------------
template<int NREF_TILE>
__global__ void knn_kernel(const float* __restrict__ qry,  // (B,3,Nq)
                           const float* __restrict__ ref,  // (B,3,Nr)
                           int* __restrict__ idx,          // (B,Nq,4)
                           int Nq, int Nr)
{
    __shared__ float rx[NREF_TILE], ry[NREF_TILE], rz[NREF_TILE], rr[NREF_TILE];
    int b = blockIdx.y;
    int n = blockIdx.x * blockDim.x + threadIdx.x;
    const float* qb = qry + (size_t)b * 3 * Nq;
    const float* rb = ref + (size_t)b * 3 * Nr;
    float qx = 0.f, qy = 0.f, qz = 0.f, qq = 0.f;
    if (n < Nq) {
        qx = qb[n]; qy = qb[Nq + n]; qz = qb[2 * Nq + n];
        qq = qx * qx + qy * qy + qz * qz;
    }
    float bd0 = INFINITY, bd1 = INFINITY, bd2 = INFINITY, bd3 = INFINITY;
    int   bi0 = 0, bi1 = 0, bi2 = 0, bi3 = 0;
    for (int m0 = 0; m0 < Nr; m0 += NREF_TILE) {
        int tile = min(NREF_TILE, Nr - m0);
        __syncthreads();
        for (int t = threadIdx.x; t < tile; t += blockDim.x) {
            float x = rb[m0 + t], y = rb[Nr + m0 + t], z = rb[2 * Nr + m0 + t];
            rx[t] = x; ry[t] = y; rz[t] = z; rr[t] = x * x + y * y + z * z;
        }
        __syncthreads();
        for (int t = 0; t < tile; ++t) {
            float dot = qx * rx[t] + qy * ry[t] + qz * rz[t];
            float d = (qq + rr[t]) - 2.0f * dot;
            if (d < bd3) {
                int m = m0 + t;
                if (d < bd2) {
                    bd3 = bd2; bi3 = bi2;
                    if (d < bd1) {
                        bd2 = bd1; bi2 = bi1;
                        if (d < bd0) { bd1 = bd0; bi1 = bi0; bd0 = d; bi0 = m; }
                        else         { bd1 = d;  bi1 = m; }
                    } else { bd2 = d; bi2 = m; }
                } else { bd3 = d; bi3 = m; }
            }
        }
    }
    if (n < Nq) {
        int4 r = make_int4(bi0, bi1, bi2, bi3);
        *reinterpret_cast<int4*>(idx + ((size_t)b * Nq + n) * 4) = r;
    }
}

// ---------------------------------------------------------------------------
// Weight prep: W1d = W1b - W1a (512x768); Wstk = [W2a ; W2b - W2a] (1536x512)
// ---------------------------------------------------------------------------
__global__ void prep_weights(const float* __restrict__ W1, const float* __restrict__ W2,
                             float* __restrict__ W1d, float* __restrict__ Wstk)
{
    int i = blockIdx.x * blockDim.x + threadIdx.x;
    if (i < C1 * CIN) {   // 512*768
        int o = i / CIN, c = i % CIN;
        W1d[i] = W1[o * (2 * CIN) + CIN + c] - W1[o * (2 * CIN) + c];
    }
    if (i < C2 * C1) {    // 768*512
        int o = i / C1, c = i % C1;
        float a = W2[o * (2 * C1) + c];
        Wstk[i] = a;
        Wstk[C2 * C1 + i] = W2[o * (2 * C1) + C1 + c] - a;
    }
}

// ---------------------------------------------------------------------------
// fp32 GEMM: C[z] = A[z] @ B[z]; 128x128 tile, BK=16, 256 thr, 8x8 microtile.
// A row-major (M,K) w/ lda; B row-major (K,N) w/ ldb; C row-major w/ ldc.
// strideA may be 0 (shared weights).
// ---------------------------------------------------------------------------
__global__ __launch_bounds__(256) void gemm128(
    const float* __restrict__ A, size_t strideA, int lda,
    const float* __restrict__ B, size_t strideB, int ldb,
    float* __restrict__ C, size_t strideC, int ldc, int K)
{
    const float* Ab = A + blockIdx.z * strideA;
    const float* Bb = B + blockIdx.z * strideB;
    float* Cb = C + blockIdx.z * strideC;
    __shared__ float As[16][132];
    __shared__ float Bs[16][132];
    int tid = threadIdx.x;
    int row0 = blockIdx.y * 128, col0 = blockIdx.x * 128;
    int tr = tid >> 4, tc = tid & 15;
    float acc[8][8] = {};
    for (int k0 = 0; k0 < K; k0 += 16) {
        #pragma unroll
        for (int q = tid; q < 512; q += 256) {
            int m = q >> 2, kk = (q & 3) << 2;
            float4 v = *reinterpret_cast<const float4*>(Ab + (size_t)(row0 + m) * lda + k0 + kk);
            As[kk + 0][m] = v.x; As[kk + 1][m] = v.y; As[kk + 2][m] = v.z; As[kk + 3][m] = v.w;
        }
        #pragma unroll
        for (int q = tid; q < 512; q += 256) {
            int kk = q >> 5, cc = (q & 31) << 2;
            float4 v = *reinterpret_cast<const float4*>(Bb + (size_t)(k0 + kk) * ldb + col0 + cc);
            *reinterpret_cast<float4*>(&Bs[kk][cc]) = v;
        }
        __syncthreads();
        #pragma unroll
        for (int k = 0; k < 16; ++k) {
            float a[8], bb[8];
            *reinterpret_cast<float4*>(a)     = *reinterpret_cast<const float4*>(&As[k][tr * 8]);
            *reinterpret_cast<float4*>(a + 4) = *reinterpret_cast<const float4*>(&As[k][tr * 8 + 4]);
            *reinterpret_cast<float4*>(bb)     = *reinterpret_cast<const float4*>(&Bs[k][tc * 8]);
            *reinterpret_cast<float4*>(bb + 4) = *reinterpret_cast<const float4*>(&Bs[k][tc * 8 + 4]);
            #pragma unroll
            for (int i = 0; i < 8; ++i)
                #pragma unroll
                for (int j = 0; j < 8; ++j)
                    acc[i][j] = fmaf(a[i], bb[j], acc[i][j]);
        }
        __syncthreads();
    }
    #pragma unroll
    for (int i = 0; i < 8; ++i) {
        size_t off = (size_t)(row0 + tr * 8 + i) * ldc + col0 + tc * 8;
        *reinterpret_cast<float4*>(Cb + off)     = make_float4(acc[i][0], acc[i][1], acc[i][2], acc[i][3]);
        *reinterpret_cast<float4*>(Cb + off + 4) = make_float4(acc[i][4], acc[i][5], acc[i][6], acc[i][7]);
    }
}

// ---------------------------------------------------------------------------
// GroupNorm stats over y[o,n,j] = P[o,idx[n,j]] + Q[o,n] per (b,group).
// One block per (o,b); atomicAdd partial (sum,sumsq) into stats[(b*4+g)*2..].
// ---------------------------------------------------------------------------
__global__ void stats_kernel(const float* __restrict__ P, size_t strideP, int ldp,
                             const float* __restrict__ Q, size_t strideQ,
                             const int* __restrict__ idx,
                             float* __restrict__ stats, int Cg, int N)
{
    int o = blockIdx.x, b = blockIdx.y;
    const float* Pr = P + b * strideP + (size_t)o * ldp;
    const float* Qr = Q + b * strideQ + (size_t)o * N;
    const int4* id = reinterpret_cast<const int4*>(idx) + (size_t)b * N;
    float s = 0.f, ss = 0.f;
    for (int n = threadIdx.x; n < N; n += blockDim.x) {
        int4 t = id[n];
        float q = Qr[n];
        float y0 = Pr[t.x] + q, y1 = Pr[t.y] + q, y2 = Pr[t.z] + q, y3 = Pr[t.w] + q;
        s  += (y0 + y1) + (y2 + y3);
        ss += y0 * y0 + y1 * y1 + y2 * y2 + y3 * y3;
    }
    #pragma unroll
    for (int off = 32; off > 0; off >>= 1) {
        s  += __shfl_down(s, off);
        ss += __shfl_down(ss, off);
    }
    __shared__ float red[8];
    int w = threadIdx.x >> 6;
    if ((threadIdx.x & 63) == 0) { red[w * 2] = s; red[w * 2 + 1] = ss; }
    __syncthreads();
    if (threadIdx.x == 0) {
        float S  = (red[0] + red[2]) + (red[4] + red[6]);
        float SS = (red[1] + red[3]) + (red[5] + red[7]);
        int g = o / Cg;
        atomicAdd(&stats[(b * 4 + g) * 2],     S);
        atomicAdd(&stats[(b * 4 + g) * 2 + 1], SS);
    }
}

// ---------------------------------------------------------------------------
// Apply GN + LeakyReLU + max over k. Monotone affine: pick max (a>=0) or min.
// out[b,o,n] = lrelu(a * ((a>=0 ? maxP : minP) + Q[o,n]) + c)
// ---------------------------------------------------------------------------
__global__ void apply_kernel(const float* __restrict__ P, size_t strideP, int ldp,
                             const float* __restrict__ Q, size_t strideQ,
                             const int* __restrict__ idx,
                             const float* __restrict__ stats,
                             const float* __restrict__ gamma, const float* __restrict__ beta,
                             float* __restrict__ out, size_t strideO,
                             int Cg, int N, float inv_count)
{
    int o = blockIdx.x, b = blockIdx.y;
    const float* Pr = P + b * strideP + (size_t)o * ldp;
    const float* Qr = Q + b * strideQ + (size_t)o * N;
    float* Or = out + b * strideO + (size_t)o * N;
    const int4* id = reinterpret_cast<const int4*>(idx) + (size_t)b * N;
    int g = o / Cg;
    float sum = stats[(b * 4 + g) * 2], sumsq = stats[(b * 4 + g) * 2 + 1];
    float mu  = sum * inv_count;
    float var = sumsq * inv_count - mu * mu;
    float a = gamma[o] * rsqrtf(var + 1e-5f);
    float c = beta[o] - a * mu;
    for (int n = threadIdx.x; n < N; n += blockDim.x) {
        int4 t = id[n];
        float p0 = Pr[t.x], p1 = Pr[t.y], p2 = Pr[t.z], p3 = Pr[t.w];
        float v = (a >= 0.f) ? fmaxf(fmaxf(p0, p1), fmaxf(p2, p3))
                             : fminf(fminf(p0, p1), fminf(p2, p3));
        v += Qr[n];
        float y = fmaf(a, v, c);
        Or[n] = y >= 0.f ? y : 0.2f * y;
    }
}

// ---------------------------------------------------------------------------
extern "C" void kernel_launch(void* const* d_in, const int* in_sizes, int n_in,
                              void* d_out, int out_size, void* d_ws, size_t ws_size,
                              hipStream_t stream)
{
    const float* coor   = (const float*)d_in[0];  // (2,3,512)
    const float* f      = (const float*)d_in[1];  // (2,768,512)
    const float* coor_q = (const float*)d_in[2];  // (2,3,4096)
    const float* f_q    = (const float*)d_in[3];  // (2,768,4096)
    const float* W1     = (const float*)d_in[4];  // (512,1536)
    const float* g1     = (const float*)d_in[5];
    const float* b1     = (const float*)d_in[6];
    const float* W2     = (const float*)d_in[7];  // (768,1024)
    const float* g2     = (const float*)d_in[8];
    const float* b2     = (const float*)d_in[9];
    float* out = (float*)d_out;                   // (2,768,4096)

    // workspace layout (bytes), all 256B-aligned segments
    char* ws = (char*)d_ws;
    size_t off = 0;
    auto alloc = [&](size_t bytes) { size_t o = off; off += (bytes + 255) & ~size_t(255); return o; };
    size_t o_idx1  = alloc((size_t)BATCH * NQ * 4 * 4);          // 131 KB
    size_t o_idx2  = alloc((size_t)BATCH * NQ * 4 * 4);
    size_t o_W1d   = alloc((size_t)C1 * CIN * 4);                // 1.5 MB
    size_t o_Wstk  = alloc((size_t)2 * C2 * C1 * 4);             // 3 MB
    size_t o_P     = alloc((size_t)BATCH * C1 * GCOARSE * 4);    // 2 MB
    size_t o_Q     = alloc((size_t)BATCH * C1 * NQ * 4);         // 16.8 MB
    size_t o_h     = alloc((size_t)BATCH * C1 * NQ * 4);         // 16.8 MB
    size_t o_RS    = alloc((size_t)BATCH * 2 * C2 * NQ * 4);     // 50.3 MB
    size_t o_stats = alloc(128);                                 // stage1: floats [0,16), stage2: [16,32)

    int*   idx1  = (int*)(ws + o_idx1);
    int*   idx2  = (int*)(ws + o_idx2);
    float* W1d   = (float*)(ws + o_W1d);
    float* Wstk  = (float*)(ws + o_Wstk);
    float* P     = (float*)(ws + o_P);
    float* Q     = (float*)(ws + o_Q);
    float* h     = (float*)(ws + o_h);
    float* RS    = (float*)(ws + o_RS);
    float* stats = (float*)(ws + o_stats);

    // 1. weight prep
    prep_weights<<<(C1 * CIN + 255) / 256, 256, 0, stream>>>(W1, W2, W1d, Wstk);

    // 2. KNN stage 1 (query=coor_q vs ref=coor) and stage 2 (self)
    knn_kernel<512><<<dim3(NQ / 256, BATCH), 256, 0, stream>>>(coor_q, coor, idx1, NQ, GCOARSE);
    knn_kernel<1024><<<dim3(NQ / 256, BATCH), 256, 0, stream>>>(coor_q, coor_q, idx2, NQ, NQ);

    // 3. P = W1a @ f  : (512x768)@(768x512)  -> (B,512,512)
    gemm128<<<dim3(GCOARSE / 128, C1 / 128, BATCH), 256, 0, stream>>>(
        W1, 0, 2 * CIN,
        f, (size_t)CIN * GCOARSE, GCOARSE,
        P, (size_t)C1 * GCOARSE, GCOARSE, CIN);

    // 4. Q = W1d @ f_q : (512x768)@(768x4096) -> (B,512,4096)
    gemm128<<<dim3(NQ / 128, C1 / 128, BATCH), 256, 0, stream>>>(
        W1d, 0, CIN,
        f_q, (size_t)CIN * NQ, NQ,
        Q, (size_t)C1 * NQ, NQ, CIN);

    // 5. GN1 stats + apply -> h   (stats floats [0,16))
    hipMemsetAsync(stats, 0, 128, stream);
    stats_kernel<<<dim3(C1, BATCH), 256, 0, stream>>>(
        P, (size_t)C1 * GCOARSE, GCOARSE,
        Q, (size_t)C1 * NQ, idx1, stats, C1 / 4, NQ);
    apply_kernel<<<dim3(C1, BATCH), 256, 0, stream>>>(
        P, (size_t)C1 * GCOARSE, GCOARSE,
        Q, (size_t)C1 * NQ, idx1, stats, g1, b1,
        h, (size_t)C1 * NQ, C1 / 4, NQ, 1.0f / ((float)(C1 / 4) * NQ * 4));

    // 6. [R;S] = Wstk @ h : (1536x512)@(512x4096) -> (B,1536,4096)
    gemm128<<<dim3(NQ / 128, (2 * C2) / 128, BATCH), 256, 0, stream>>>(
        Wstk, 0, C1,
        h, (size_t)C1 * NQ, NQ,
        RS, (size_t)2 * C2 * NQ, NQ, C1);

    // 7. GN2 stats + apply -> out.  R = RS rows [0,768), S = rows [768,1536)
    //    stats floats [16,32) — DISJOINT from stage 1 (round-1 bug: was +8, overlapped)
    stats_kernel<<<dim3(C2, BATCH), 256, 0, stream>>>(
        RS, (size_t)2 * C2 * NQ, NQ,
        RS + (size_t)C2 * NQ, (size_t)2 * C2 * NQ, idx2, stats + 16, C2 / 4, NQ);
    apply_kernel<<<dim3(C2, BATCH), 256, 0, stream>>>(
        RS, (size_t)2 * C2 * NQ, NQ,
        RS + (size_t)C2 * NQ, (size_t)2 * C2 * NQ, idx2, stats + 16, g2, b2,
        out, (size_t)C2 * NQ, C2 / 4, NQ, 1.0f / ((float)(C2 / 4) * NQ * 4));
}

// Round 3
// 583.536 us; speedup vs baseline: 1.9689x; 1.9689x over previous
//
#include <hip/hip_runtime.h>

// Problem constants: B=2, G=512, N=4096, C=768, k=4
#define BATCH 2
#define GCOARSE 512
#define NQ 4096
#define CIN 768
#define C1 512
#define C2 768

typedef __attribute__((ext_vector_type(8))) short bf16x8;
typedef __attribute__((ext_vector_type(4))) float f32x4;

__device__ __forceinline__ unsigned short f2bf(float x) {
    unsigned u = __builtin_bit_cast(unsigned, x);
    unsigned r = (u + 0x7FFFu + ((u >> 16) & 1u)) >> 16;   // RNE
    return (unsigned short)r;
}
__device__ __forceinline__ float ld_f(const float* p) { return *p; }
__device__ __forceinline__ float ld_f(const unsigned short* p) {
    unsigned v = (unsigned)(*p) << 16;
    return __builtin_bit_cast(float, v);
}
__device__ __forceinline__ void st_v(float* p, float v) { *p = v; }
__device__ __forceinline__ void st_v(unsigned short* p, float v) { *p = f2bf(v); }

// ---------------------------------------------------------------------------
// top-4 insertion, strict < keeps earliest-encountered on ties (== top_k ties)
// ---------------------------------------------------------------------------
__device__ __forceinline__ void ins4(float d, int m,
                                     float& bd0, float& bd1, float& bd2, float& bd3,
                                     int& bi0, int& bi1, int& bi2, int& bi3)
{
    if (d < bd3) {
        if (d < bd2) {
            bd3 = bd2; bi3 = bi2;
            if (d < bd1) {
                bd2 = bd1; bi2 = bi1;
                if (d < bd0) { bd1 = bd0; bi1 = bi0; bd0 = d; bi0 = m; }
                else         { bd1 = d;  bi1 = m; }
            } else { bd2 = d; bi2 = m; }
        } else { bd3 = d; bi3 = m; }
    }
}

// ---------------------------------------------------------------------------
// KNN split: block = (256 queries) x (one ref chunk of CH). Writes per-chunk
// top-4 candidates to cand buffers [B*Nq][RSPLIT][4].
// ---------------------------------------------------------------------------
template<int CH>
__global__ void knn_split(const float* __restrict__ qry, const float* __restrict__ ref,
                          float* __restrict__ cd, int* __restrict__ ci,
                          int Nq, int Nr, int rsplit)
{
    __shared__ float rx[CH], ry[CH], rz[CH], rr[CH];
    int b = blockIdx.z, rc = blockIdx.y;
    int n = blockIdx.x * 256 + threadIdx.x;
    int m0 = rc * CH;
    const float* qb = qry + (size_t)b * 3 * Nq;
    const float* rb = ref + (size_t)b * 3 * Nr;
    for (int t = threadIdx.x; t < CH; t += 256) {
        float x = rb[m0 + t], y = rb[Nr + m0 + t], z = rb[2 * Nr + m0 + t];
        rx[t] = x; ry[t] = y; rz[t] = z; rr[t] = x * x + y * y + z * z;
    }
    __syncthreads();
    float qx = qb[n], qy = qb[Nq + n], qz = qb[2 * Nq + n];
    float qq = qx * qx + qy * qy + qz * qz;
    float bd0 = INFINITY, bd1 = INFINITY, bd2 = INFINITY, bd3 = INFINITY;
    int   bi0 = 0, bi1 = 0, bi2 = 0, bi3 = 0;
    #pragma unroll 8
    for (int t = 0; t < CH; ++t) {
        float dot = qx * rx[t] + qy * ry[t] + qz * rz[t];
        float d = (qq + rr[t]) - 2.0f * dot;
        ins4(d, m0 + t, bd0, bd1, bd2, bd3, bi0, bi1, bi2, bi3);
    }
    size_t o = ((size_t)(b * Nq + n) * rsplit + rc) * 4;
    *reinterpret_cast<float4*>(cd + o) = make_float4(bd0, bd1, bd2, bd3);
    *reinterpret_cast<int4*>(ci + o)   = make_int4(bi0, bi1, bi2, bi3);
}

template<int RSP>
__global__ void knn_merge(const float* __restrict__ cd, const int* __restrict__ ci,
                          int* __restrict__ idx, int total)
{
    int q = blockIdx.x * 256 + threadIdx.x;
    if (q >= total) return;
    const float* d = cd + (size_t)q * RSP * 4;
    const int* ii  = ci + (size_t)q * RSP * 4;
    float bd0 = INFINITY, bd1 = INFINITY, bd2 = INFINITY, bd3 = INFINITY;
    int   bi0 = 0, bi1 = 0, bi2 = 0, bi3 = 0;
    #pragma unroll
    for (int t = 0; t < RSP * 4; ++t)
        ins4(d[t], ii[t], bd0, bd1, bd2, bd3, bi0, bi1, bi2, bi3);
    *reinterpret_cast<int4*>(idx + (size_t)q * 4) = make_int4(bi0, bi1, bi2, bi3);
}

// ---------------------------------------------------------------------------
// Weight prep -> bf16: W1a (512x768), W1d = W1b-W1a (512x768),
// Wstk = [W2a ; W2b-W2a] (1536x512)
// ---------------------------------------------------------------------------
__global__ void prep_weights_bf(const float* __restrict__ W1, const float* __restrict__ W2,
                                unsigned short* __restrict__ W1a, unsigned short* __restrict__ W1d,
                                unsigned short* __restrict__ Wstk)
{
    int i = blockIdx.x * blockDim.x + threadIdx.x;
    if (i < C1 * CIN) {
        int o = i / CIN, c = i % CIN;
        float a = W1[o * 2 * CIN + c], b = W1[o * 2 * CIN + CIN + c];
        W1a[i] = f2bf(a);
        W1d[i] = f2bf(b - a);
    }
    if (i < C2 * C1) {
        int o = i / C1, c = i % C1;
        float a = W2[o * 2 * C1 + c], b = W2[o * 2 * C1 + C1 + c];
        Wstk[i] = f2bf(a);
        Wstk[C2 * C1 + i] = f2bf(b - a);
    }
}

// ---------------------------------------------------------------------------
// Transpose + convert to bf16: in (B, Cdim, Ndim) IT -> out (B, Ndim, Cdim) bf16
// ---------------------------------------------------------------------------
template<typename IT>
__global__ void transposeT_bf16(const IT* __restrict__ in, unsigned short* __restrict__ out,
                                int Cdim, int Ndim)
{
    __shared__ float t[32][33];
    int b = blockIdx.z;
    int n0 = blockIdx.x * 32, c0 = blockIdx.y * 32;
    const IT* ib = in + (size_t)b * Cdim * Ndim;
    unsigned short* ob = out + (size_t)b * Cdim * Ndim;
    int tx = threadIdx.x, ty = threadIdx.y;
    #pragma unroll
    for (int j = 0; j < 4; ++j)
        t[ty + j * 8][tx] = ld_f(&ib[(size_t)(c0 + ty + j * 8) * Ndim + n0 + tx]);
    __syncthreads();
    #pragma unroll
    for (int j = 0; j < 4; ++j)
        ob[(size_t)(n0 + ty + j * 8) * Cdim + c0 + tx] = f2bf(t[tx][ty + j * 8]);
}

// ---------------------------------------------------------------------------
// bf16 MFMA GEMM: C[M][N] = A[M][K] @ BT[N][K]^T, fp32 out.
// Block tile BM=32*FM x BN=32*FN, 4 waves (2x2), wave tile 16FM x 16FN,
// BK=32, reg-staged LDS, single-buffered 2-barrier loop.
// A/B fragment: row/col = lane&15, k = (lane>>4)*8 + j (contiguous 8 bf16).
// C/D: col = lane&15, row = (lane>>4)*4 + reg   [m89-verified]
// ---------------------------------------------------------------------------
template<int FM, int FN>
__global__ __launch_bounds__(256) void gemm_mfma(
    const unsigned short* __restrict__ A, size_t strideA,
    const unsigned short* __restrict__ BT, size_t strideB,
    float* __restrict__ C, size_t strideC,
    int M, int N, int K)
{
    constexpr int BM = 32 * FM, BN = 32 * FN;
    const unsigned short* Ab = A + blockIdx.z * strideA;
    const unsigned short* Bb = BT + blockIdx.z * strideB;
    float* Cb = C + blockIdx.z * strideC;
    __shared__ __align__(16) unsigned short As[BM * 32];
    __shared__ __align__(16) unsigned short Bs[BN * 32];
    int tid = threadIdx.x;
    int lane = tid & 63, w = tid >> 6;
    int wr = w >> 1, wc = w & 1;
    int lr = lane & 15, kh = lane >> 4;
    int row0 = blockIdx.y * BM, col0 = blockIdx.x * BN;
    f32x4 acc[FM][FN] = {};
    for (int k0 = 0; k0 < K; k0 += 32) {
        __syncthreads();
        #pragma unroll
        for (int c = tid; c < BM * 4; c += 256) {
            int r = c >> 2, cc = c & 3;
            bf16x8 v = *reinterpret_cast<const bf16x8*>(Ab + (size_t)(row0 + r) * K + k0 + cc * 8);
            *reinterpret_cast<bf16x8*>(&As[c * 8]) = v;
        }
        #pragma unroll
        for (int c = tid; c < BN * 4; c += 256) {
            int r = c >> 2, cc = c & 3;
            bf16x8 v = *reinterpret_cast<const bf16x8*>(Bb + (size_t)(col0 + r) * K + k0 + cc * 8);
            *reinterpret_cast<bf16x8*>(&Bs[c * 8]) = v;
        }
        __syncthreads();
        bf16x8 af[FM], bf[FN];
        #pragma unroll
        for (int mt = 0; mt < FM; ++mt)
            af[mt] = *reinterpret_cast<const bf16x8*>(&As[(wr * 16 * FM + mt * 16 + lr) * 32 + kh * 8]);
        #pragma unroll
        for (int nt = 0; nt < FN; ++nt)
            bf[nt] = *reinterpret_cast<const bf16x8*>(&Bs[(wc * 16 * FN + nt * 16 + lr) * 32 + kh * 8]);
        #pragma unroll
        for (int mt = 0; mt < FM; ++mt)
            #pragma unroll
            for (int nt = 0; nt < FN; ++nt)
                acc[mt][nt] = __builtin_amdgcn_mfma_f32_16x16x32_bf16(af[mt], bf[nt], acc[mt][nt], 0, 0, 0);
    }
    #pragma unroll
    for (int mt = 0; mt < FM; ++mt)
        #pragma unroll
        for (int nt = 0; nt < FN; ++nt)
            #pragma unroll
            for (int r = 0; r < 4; ++r) {
                int row = row0 + wr * 16 * FM + mt * 16 + kh * 4 + r;
                int col = col0 + wc * 16 * FN + nt * 16 + lr;
                Cb[(size_t)row * N + col] = acc[mt][nt][r];
            }
}

// ---------------------------------------------------------------------------
// GroupNorm stats over y[o,n,j] = P[o,idx[n,j]] + Q[o,n]
// ---------------------------------------------------------------------------
__global__ void stats_kernel(const float* __restrict__ P, size_t strideP, int ldp,
                             const float* __restrict__ Q, size_t strideQ,
                             const int* __restrict__ idx,
                             float* __restrict__ stats, int Cg, int N)
{
    int o = blockIdx.x, b = blockIdx.y;
    const float* Pr = P + b * strideP + (size_t)o * ldp;
    const float* Qr = Q + b * strideQ + (size_t)o * N;
    const int4* id = reinterpret_cast<const int4*>(idx) + (size_t)b * N;
    float s = 0.f, ss = 0.f;
    for (int n = threadIdx.x; n < N; n += blockDim.x) {
        int4 t = id[n];
        float q = Qr[n];
        float y0 = Pr[t.x] + q, y1 = Pr[t.y] + q, y2 = Pr[t.z] + q, y3 = Pr[t.w] + q;
        s  += (y0 + y1) + (y2 + y3);
        ss += y0 * y0 + y1 * y1 + y2 * y2 + y3 * y3;
    }
    #pragma unroll
    for (int off = 32; off > 0; off >>= 1) {
        s  += __shfl_down(s, off);
        ss += __shfl_down(ss, off);
    }
    __shared__ float red[8];
    int w = threadIdx.x >> 6;
    if ((threadIdx.x & 63) == 0) { red[w * 2] = s; red[w * 2 + 1] = ss; }
    __syncthreads();
    if (threadIdx.x == 0) {
        float S  = (red[0] + red[2]) + (red[4] + red[6]);
        float SS = (red[1] + red[3]) + (red[5] + red[7]);
        int g = o / Cg;
        atomicAdd(&stats[(b * 4 + g) * 2],     S);
        atomicAdd(&stats[(b * 4 + g) * 2 + 1], SS);
    }
}

// ---------------------------------------------------------------------------
// Apply GN + LeakyReLU + max over k (monotone affine: max or min of gathered P)
// ---------------------------------------------------------------------------
template<typename OT>
__global__ void apply_kernel(const float* __restrict__ P, size_t strideP, int ldp,
                             const float* __restrict__ Q, size_t strideQ,
                             const int* __restrict__ idx,
                             const float* __restrict__ stats,
                             const float* __restrict__ gamma, const float* __restrict__ beta,
                             OT* __restrict__ out, size_t strideO,
                             int Cg, int N, float inv_count)
{
    int o = blockIdx.x, b = blockIdx.y;
    const float* Pr = P + b * strideP + (size_t)o * ldp;
    const float* Qr = Q + b * strideQ + (size_t)o * N;
    OT* Or = out + b * strideO + (size_t)o * N;
    const int4* id = reinterpret_cast<const int4*>(idx) + (size_t)b * N;
    int g = o / Cg;
    float sum = stats[(b * 4 + g) * 2], sumsq = stats[(b * 4 + g) * 2 + 1];
    float mu  = sum * inv_count;
    float var = sumsq * inv_count - mu * mu;
    float a = gamma[o] * rsqrtf(var + 1e-5f);
    float c = beta[o] - a * mu;
    for (int n = threadIdx.x; n < N; n += blockDim.x) {
        int4 t = id[n];
        float p0 = Pr[t.x], p1 = Pr[t.y], p2 = Pr[t.z], p3 = Pr[t.w];
        float v = (a >= 0.f) ? fmaxf(fmaxf(p0, p1), fmaxf(p2, p3))
                             : fminf(fminf(p0, p1), fminf(p2, p3));
        v += Qr[n];
        float y = fmaf(a, v, c);
        st_v(&Or[n], y >= 0.f ? y : 0.2f * y);
    }
}

// ---------------------------------------------------------------------------
extern "C" void kernel_launch(void* const* d_in, const int* in_sizes, int n_in,
                              void* d_out, int out_size, void* d_ws, size_t ws_size,
                              hipStream_t stream)
{
    const float* coor   = (const float*)d_in[0];
    const float* f      = (const float*)d_in[1];
    const float* coor_q = (const float*)d_in[2];
    const float* f_q    = (const float*)d_in[3];
    const float* W1     = (const float*)d_in[4];
    const float* g1     = (const float*)d_in[5];
    const float* b1     = (const float*)d_in[6];
    const float* W2     = (const float*)d_in[7];
    const float* g2     = (const float*)d_in[8];
    const float* b2     = (const float*)d_in[9];
    float* out = (float*)d_out;

    char* ws = (char*)d_ws;
    size_t off = 0;
    auto alloc = [&](size_t bytes) { size_t o = off; off += (bytes + 255) & ~size_t(255); return o; };
    size_t o_idx1 = alloc((size_t)BATCH * NQ * 4 * 4);
    size_t o_idx2 = alloc((size_t)BATCH * NQ * 4 * 4);
    size_t o_W1a  = alloc((size_t)C1 * CIN * 2);
    size_t o_W1d  = alloc((size_t)C1 * CIN * 2);
    size_t o_Wstk = alloc((size_t)2 * C2 * C1 * 2);
    size_t o_fT   = alloc((size_t)BATCH * GCOARSE * CIN * 2);   // (B,G,C) bf16
    size_t o_fqT  = alloc((size_t)BATCH * NQ * CIN * 2);        // (B,N,C) bf16; later reused for h_bf (B,C1,N) bf16 (8.4MB<=12.6MB)
    size_t o_P    = alloc((size_t)BATCH * C1 * GCOARSE * 4);
    size_t o_Q    = alloc((size_t)BATCH * C1 * NQ * 4);         // later reused for hT (B,N,C1) bf16 (8.4MB<=16.8MB)
    size_t o_RS   = alloc((size_t)BATCH * 2 * C2 * NQ * 4);     // first 6MB reused for knn cand buffers
    size_t o_stats = alloc(128);
    (void)ws_size;

    int* idx1 = (int*)(ws + o_idx1);
    int* idx2 = (int*)(ws + o_idx2);
    unsigned short* W1a  = (unsigned short*)(ws + o_W1a);
    unsigned short* W1d  = (unsigned short*)(ws + o_W1d);
    unsigned short* Wstk = (unsigned short*)(ws + o_Wstk);
    unsigned short* fT   = (unsigned short*)(ws + o_fT);
    unsigned short* fqT  = (unsigned short*)(ws + o_fqT);
    unsigned short* h_bf = (unsigned short*)(ws + o_fqT);       // alias (f_qT dead after Q-gemm)
    float* P  = (float*)(ws + o_P);
    float* Q  = (float*)(ws + o_Q);
    unsigned short* hT = (unsigned short*)(ws + o_Q);           // alias (Q dead after apply1)
    float* RS = (float*)(ws + o_RS);
    float* cd2 = (float*)(ws + o_RS);                           // 2MB
    int*   ci2 = (int*)(ws + o_RS + (size_t)2 * 1024 * 1024);   // 2MB
    float* cd1 = (float*)(ws + o_RS + (size_t)4 * 1024 * 1024); // 1MB
    int*   ci1 = (int*)(ws + o_RS + (size_t)5 * 1024 * 1024);   // 1MB
    float* stats = (float*)(ws + o_stats);

    // 1. weights -> bf16 (+ diff / stack transforms)
    prep_weights_bf<<<(C1 * CIN + 255) / 256, 256, 0, stream>>>(W1, W2, W1a, W1d, Wstk);

    // 2. activations -> transposed bf16 (N-major, K contiguous)
    transposeT_bf16<float><<<dim3(NQ / 32, CIN / 32, BATCH), dim3(32, 8), 0, stream>>>(f_q, fqT, CIN, NQ);
    transposeT_bf16<float><<<dim3(GCOARSE / 32, CIN / 32, BATCH), dim3(32, 8), 0, stream>>>(f, fT, CIN, GCOARSE);

    // 3. KNN split + merge (cand buffers alias RS region; RS written later)
    knn_split<64><<<dim3(NQ / 256, 8, BATCH), 256, 0, stream>>>(coor_q, coor, cd1, ci1, NQ, GCOARSE, 8);
    knn_merge<8><<<(BATCH * NQ + 255) / 256, 256, 0, stream>>>(cd1, ci1, idx1, BATCH * NQ);
    knn_split<256><<<dim3(NQ / 256, 16, BATCH), 256, 0, stream>>>(coor_q, coor_q, cd2, ci2, NQ, NQ, 16);
    knn_merge<16><<<(BATCH * NQ + 255) / 256, 256, 0, stream>>>(cd2, ci2, idx2, BATCH * NQ);

    // 4. P = W1a @ f : (512x768)@(768x512) -> (B,512,512)
    gemm_mfma<2, 2><<<dim3(GCOARSE / 64, C1 / 64, BATCH), 256, 0, stream>>>(
        W1a, 0, fT, (size_t)GCOARSE * CIN, P, (size_t)C1 * GCOARSE, C1, GCOARSE, CIN);

    // 5. Q = W1d @ f_q : (512x768)@(768x4096) -> (B,512,4096)
    gemm_mfma<2, 4><<<dim3(NQ / 128, C1 / 64, BATCH), 256, 0, stream>>>(
        W1d, 0, fqT, (size_t)NQ * CIN, Q, (size_t)C1 * NQ, C1, NQ, CIN);

    // 6. GN1 stats + apply -> h_bf (bf16, over f_qT region)
    hipMemsetAsync(stats, 0, 128, stream);
    stats_kernel<<<dim3(C1, BATCH), 256, 0, stream>>>(
        P, (size_t)C1 * GCOARSE, GCOARSE, Q, (size_t)C1 * NQ, idx1, stats, C1 / 4, NQ);
    apply_kernel<unsigned short><<<dim3(C1, BATCH), 256, 0, stream>>>(
        P, (size_t)C1 * GCOARSE, GCOARSE, Q, (size_t)C1 * NQ, idx1, stats, g1, b1,
        h_bf, (size_t)C1 * NQ, C1 / 4, NQ, 1.0f / ((float)(C1 / 4) * NQ * 4));

    // 7. hT = transpose(h_bf) -> (B,N,C1) bf16 (over Q region; Q dead)
    transposeT_bf16<unsigned short><<<dim3(NQ / 32, C1 / 32, BATCH), dim3(32, 8), 0, stream>>>(h_bf, hT, C1, NQ);

    // 8. [R;S] = Wstk @ h : (1536x512)@(512x4096) -> (B,1536,4096) (overwrites cand)
    gemm_mfma<4, 4><<<dim3(NQ / 128, (2 * C2) / 128, BATCH), 256, 0, stream>>>(
        Wstk, 0, hT, (size_t)NQ * C1, RS, (size_t)2 * C2 * NQ, 2 * C2, NQ, C1);

    // 9. GN2 stats + apply -> out (stats floats [16,32), disjoint from stage 1)
    stats_kernel<<<dim3(C2, BATCH), 256, 0, stream>>>(
        RS, (size_t)2 * C2 * NQ, NQ,
        RS + (size_t)C2 * NQ, (size_t)2 * C2 * NQ, idx2, stats + 16, C2 / 4, NQ);
    apply_kernel<float><<<dim3(C2, BATCH), 256, 0, stream>>>(
        RS, (size_t)2 * C2 * NQ, NQ,
        RS + (size_t)C2 * NQ, (size_t)2 * C2 * NQ, idx2, stats + 16, g2, b2,
        out, (size_t)C2 * NQ, C2 / 4, NQ, 1.0f / ((float)(C2 / 4) * NQ * 4));
}

// Round 6
// 578.084 us; speedup vs baseline: 1.9875x; 1.0094x over previous
//
#include <hip/hip_runtime.h>

// Problem constants: B=2, G=512, N=4096, C=768, k=4
#define BATCH 2
#define GCOARSE 512
#define NQ 4096
#define CIN 768
#define C1 512
#define C2 768

typedef __attribute__((ext_vector_type(8))) short bf16x8;
typedef __attribute__((ext_vector_type(4))) float f32x4;

__device__ __forceinline__ unsigned short f2bf(float x) {
    unsigned u = __builtin_bit_cast(unsigned, x);
    unsigned r = (u + 0x7FFFu + ((u >> 16) & 1u)) >> 16;   // RNE
    return (unsigned short)r;
}
__device__ __forceinline__ float ld_f(const float* p) { return *p; }
__device__ __forceinline__ float ld_f(const unsigned short* p) {
    unsigned v = (unsigned)(*p) << 16;
    return __builtin_bit_cast(float, v);
}
__device__ __forceinline__ void st_v(float* p, float v) { *p = v; }
__device__ __forceinline__ void st_v(unsigned short* p, float v) { *p = f2bf(v); }

// async global->LDS, 16B per lane; LDS dest = wave-uniform base + lane*16
__device__ __forceinline__ void gload16(const void* g, void* l) {
    __builtin_amdgcn_global_load_lds(
        (const __attribute__((address_space(1))) unsigned int*)g,
        (__attribute__((address_space(3))) unsigned int*)l,
        16, 0, 0);
}

// ---------------------------------------------------------------------------
// KNN insert — ROUND-2 VERBATIM (FROZEN). The distance selection is
// ULP-fragile vs the numpy reference (r4/r5 post-mortem): any change to this
// code or the distance expressions below risks flipping a near-tie neighbor.
// ---------------------------------------------------------------------------
__device__ __forceinline__ void ins4(float d, int m,
                                     float& bd0, float& bd1, float& bd2, float& bd3,
                                     int& bi0, int& bi1, int& bi2, int& bi3)
{
    if (d < bd3) {
        if (d < bd2) {
            bd3 = bd2; bi3 = bi2;
            if (d < bd1) {
                bd2 = bd1; bi2 = bi1;
                if (d < bd0) { bd1 = bd0; bi1 = bi0; bd0 = d; bi0 = m; }
                else         { bd1 = d;  bi1 = m; }
            } else { bd2 = d; bi2 = m; }
        } else { bd3 = d; bi3 = m; }
    }
}

// ---------------------------------------------------------------------------
// KNN split — ROUND-2 VERBATIM (FROZEN, see above).
// ---------------------------------------------------------------------------
template<int CH>
__global__ void knn_split(const float* __restrict__ qry, const float* __restrict__ ref,
                          float* __restrict__ cd, int* __restrict__ ci,
                          int Nq, int Nr, int rsplit)
{
    __shared__ float rx[CH], ry[CH], rz[CH], rr[CH];
    int b = blockIdx.z, rc = blockIdx.y;
    int n = blockIdx.x * 256 + threadIdx.x;
    int m0 = rc * CH;
    const float* qb = qry + (size_t)b * 3 * Nq;
    const float* rb = ref + (size_t)b * 3 * Nr;
    for (int t = threadIdx.x; t < CH; t += 256) {
        float x = rb[m0 + t], y = rb[Nr + m0 + t], z = rb[2 * Nr + m0 + t];
        rx[t] = x; ry[t] = y; rz[t] = z; rr[t] = x * x + y * y + z * z;
    }
    __syncthreads();
    float qx = qb[n], qy = qb[Nq + n], qz = qb[2 * Nq + n];
    float qq = qx * qx + qy * qy + qz * qz;
    float bd0 = INFINITY, bd1 = INFINITY, bd2 = INFINITY, bd3 = INFINITY;
    int   bi0 = 0, bi1 = 0, bi2 = 0, bi3 = 0;
    #pragma unroll 8
    for (int t = 0; t < CH; ++t) {
        float dot = qx * rx[t] + qy * ry[t] + qz * rz[t];
        float d = (qq + rr[t]) - 2.0f * dot;
        ins4(d, m0 + t, bd0, bd1, bd2, bd3, bi0, bi1, bi2, bi3);
    }
    size_t o = ((size_t)(b * Nq + n) * rsplit + rc) * 4;
    *reinterpret_cast<float4*>(cd + o) = make_float4(bd0, bd1, bd2, bd3);
    *reinterpret_cast<int4*>(ci + o)   = make_int4(bi0, bi1, bi2, bi3);
}

template<int RSP>
__global__ void knn_merge(const float* __restrict__ cd, const int* __restrict__ ci,
                          int* __restrict__ idx, int total)
{
    int q = blockIdx.x * 256 + threadIdx.x;
    if (q >= total) return;
    const float* d = cd + (size_t)q * RSP * 4;
    const int* ii  = ci + (size_t)q * RSP * 4;
    float bd0 = INFINITY, bd1 = INFINITY, bd2 = INFINITY, bd3 = INFINITY;
    int   bi0 = 0, bi1 = 0, bi2 = 0, bi3 = 0;
    #pragma unroll
    for (int t = 0; t < RSP * 4; ++t)
        ins4(d[t], ii[t], bd0, bd1, bd2, bd3, bi0, bi1, bi2, bi3);
    *reinterpret_cast<int4*>(idx + (size_t)q * 4) = make_int4(bi0, bi1, bi2, bi3);
}

// ---------------------------------------------------------------------------
// Weight prep -> bf16
// ---------------------------------------------------------------------------
__global__ void prep_weights_bf(const float* __restrict__ W1, const float* __restrict__ W2,
                                unsigned short* __restrict__ W1a, unsigned short* __restrict__ W1d,
                                unsigned short* __restrict__ Wstk)
{
    int i = blockIdx.x * blockDim.x + threadIdx.x;
    if (i < C1 * CIN) {
        int o = i / CIN, c = i % CIN;
        float a = W1[o * 2 * CIN + c], b = W1[o * 2 * CIN + CIN + c];
        W1a[i] = f2bf(a);
        W1d[i] = f2bf(b - a);
    }
    if (i < C2 * C1) {
        int o = i / C1, c = i % C1;
        float a = W2[o * 2 * C1 + c], b = W2[o * 2 * C1 + C1 + c];
        Wstk[i] = f2bf(a);
        Wstk[C2 * C1 + i] = f2bf(b - a);
    }
}

// ---------------------------------------------------------------------------
// Transpose + convert to bf16: in (B, Cdim, Ndim) IT -> out (B, Ndim, Cdim) bf16
// ---------------------------------------------------------------------------
template<typename IT>
__global__ void transposeT_bf16(const IT* __restrict__ in, unsigned short* __restrict__ out,
                                int Cdim, int Ndim)
{
    __shared__ float t[32][33];
    int b = blockIdx.z;
    int n0 = blockIdx.x * 32, c0 = blockIdx.y * 32;
    const IT* ib = in + (size_t)b * Cdim * Ndim;
    unsigned short* ob = out + (size_t)b * Cdim * Ndim;
    int tx = threadIdx.x, ty = threadIdx.y;
    #pragma unroll
    for (int j = 0; j < 4; ++j)
        t[ty + j * 8][tx] = ld_f(&ib[(size_t)(c0 + ty + j * 8) * Ndim + n0 + tx]);
    __syncthreads();
    #pragma unroll
    for (int j = 0; j < 4; ++j)
        ob[(size_t)(n0 + ty + j * 8) * Cdim + c0 + tx] = f2bf(t[tx][ty + j * 8]);
}

// ---------------------------------------------------------------------------
// bf16 MFMA GEMM, m97 structure: C[M][N] = A[M][K] @ BT[N][K]^T, fp32 out.
// Block BM x BN (BM=32*FM), 4 waves 2x2, wave tile 16FM x 16FN, BK=32.
// Staging: global_load_lds width 16 into linear K-major LDS [rows][32]bf16.
// Mapping proof: lane l covers row (l>>2), bf16 cols [(l&3)*8, +8) of each
// 16x32 sub-block == LDS linear dest base + l*16B. (r4/r5 absmax identity
// also empirically supports gload == reg-staged bitwise.)
// ---------------------------------------------------------------------------
template<int FM, int FN>
__global__ __launch_bounds__(256) void gemm_mfma(
    const unsigned short* __restrict__ A, size_t strideA,
    const unsigned short* __restrict__ BT, size_t strideB,
    float* __restrict__ C, size_t strideC,
    int N, int K)
{
    constexpr int BM = 32 * FM, BN = 32 * FN;
    constexpr int AI = BM / 64, BI = BN / 64;   // gload_lds instrs per wave
    __shared__ __align__(16) unsigned short As[BM * 32];
    __shared__ __align__(16) unsigned short Bs[BN * 32];
    const unsigned short* Ab = A + blockIdx.z * strideA;
    const unsigned short* Bb = BT + blockIdx.z * strideB;
    float* Cb = C + blockIdx.z * strideC;
    const int tid = threadIdx.x, lane = tid & 63, w = tid >> 6;
    const int wr = w >> 1, wc = w & 1;
    const int lr = lane & 15, kh = lane >> 4;
    const int row0 = blockIdx.y * BM, col0 = blockIdx.x * BN;
    const int srow = lane >> 2, scol = (lane & 3) * 8;   // 16 rows x 4 chunks per instr
    const unsigned short* gA = Ab + (size_t)(row0 + w * (BM / 4) + srow) * K + scol;
    const unsigned short* gB = Bb + (size_t)(col0 + w * (BN / 4) + srow) * K + scol;
    unsigned short* lA = &As[(w * (BM / 4)) * 32];
    unsigned short* lB = &Bs[(w * (BN / 4)) * 32];
    f32x4 acc[FM][FN] = {};
    for (int k0 = 0; k0 < K; k0 += 32) {
        __syncthreads();   // previous tile fully consumed
        #pragma unroll
        for (int i = 0; i < AI; ++i)
            gload16(gA + (size_t)i * 16 * K + k0, lA + i * 16 * 32);
        #pragma unroll
        for (int i = 0; i < BI; ++i)
            gload16(gB + (size_t)i * 16 * K + k0, lB + i * 16 * 32);
        __syncthreads();   // compiler emits vmcnt(0) drain before barrier
        bf16x8 af[FM], bfr[FN];
        #pragma unroll
        for (int mt = 0; mt < FM; ++mt)
            af[mt] = *reinterpret_cast<const bf16x8*>(&As[(wr * 16 * FM + mt * 16 + lr) * 32 + kh * 8]);
        #pragma unroll
        for (int nt = 0; nt < FN; ++nt)
            bfr[nt] = *reinterpret_cast<const bf16x8*>(&Bs[(wc * 16 * FN + nt * 16 + lr) * 32 + kh * 8]);
        #pragma unroll
        for (int mt = 0; mt < FM; ++mt)
            #pragma unroll
            for (int nt = 0; nt < FN; ++nt)
                acc[mt][nt] = __builtin_amdgcn_mfma_f32_16x16x32_bf16(af[mt], bfr[nt], acc[mt][nt], 0, 0, 0);
    }
    #pragma unroll
    for (int mt = 0; mt < FM; ++mt)
        #pragma unroll
        for (int nt = 0; nt < FN; ++nt)
            #pragma unroll
            for (int r = 0; r < 4; ++r) {
                int row = row0 + wr * 16 * FM + mt * 16 + kh * 4 + r;
                int col = col0 + wc * 16 * FN + nt * 16 + lr;
                Cb[(size_t)row * N + col] = acc[mt][nt][r];
            }
}

// ---------------------------------------------------------------------------
// GroupNorm stats over y[o,n,j] = P[o,idx[n,j]] + Q[o,n]
// ---------------------------------------------------------------------------
__global__ void stats_kernel(const float* __restrict__ P, size_t strideP, int ldp,
                             const float* __restrict__ Q, size_t strideQ,
                             const int* __restrict__ idx,
                             float* __restrict__ stats, int Cg, int N)
{
    int o = blockIdx.x, b = blockIdx.y;
    const float* Pr = P + b * strideP + (size_t)o * ldp;
    const float* Qr = Q + b * strideQ + (size_t)o * N;
    const int4* id = reinterpret_cast<const int4*>(idx) + (size_t)b * N;
    float s = 0.f, ss = 0.f;
    for (int n = threadIdx.x; n < N; n += blockDim.x) {
        int4 t = id[n];
        float q = Qr[n];
        float y0 = Pr[t.x] + q, y1 = Pr[t.y] + q, y2 = Pr[t.z] + q, y3 = Pr[t.w] + q;
        s  += (y0 + y1) + (y2 + y3);
        ss += y0 * y0 + y1 * y1 + y2 * y2 + y3 * y3;
    }
    #pragma unroll
    for (int off = 32; off > 0; off >>= 1) {
        s  += __shfl_down(s, off);
        ss += __shfl_down(ss, off);
    }
    __shared__ float red[8];
    int w = threadIdx.x >> 6;
    if ((threadIdx.x & 63) == 0) { red[w * 2] = s; red[w * 2 + 1] = ss; }
    __syncthreads();
    if (threadIdx.x == 0) {
        float S  = (red[0] + red[2]) + (red[4] + red[6]);
        float SS = (red[1] + red[3]) + (red[5] + red[7]);
        int g = o / Cg;
        atomicAdd(&stats[(b * 4 + g) * 2],     S);
        atomicAdd(&stats[(b * 4 + g) * 2 + 1], SS);
    }
}

// ---------------------------------------------------------------------------
// Apply GN + LeakyReLU + max over k (monotone affine: max or min of gathered P)
// ---------------------------------------------------------------------------
template<typename OT>
__global__ void apply_kernel(const float* __restrict__ P, size_t strideP, int ldp,
                             const float* __restrict__ Q, size_t strideQ,
                             const int* __restrict__ idx,
                             const float* __restrict__ stats,
                             const float* __restrict__ gamma, const float* __restrict__ beta,
                             OT* __restrict__ out, size_t strideO,
                             int Cg, int N, float inv_count)
{
    int o = blockIdx.x, b = blockIdx.y;
    const float* Pr = P + b * strideP + (size_t)o * ldp;
    const float* Qr = Q + b * strideQ + (size_t)o * N;
    OT* Or = out + b * strideO + (size_t)o * N;
    const int4* id = reinterpret_cast<const int4*>(idx) + (size_t)b * N;
    int g = o / Cg;
    float sum = stats[(b * 4 + g) * 2], sumsq = stats[(b * 4 + g) * 2 + 1];
    float mu  = sum * inv_count;
    float var = sumsq * inv_count - mu * mu;
    float a = gamma[o] * rsqrtf(var + 1e-5f);
    float c = beta[o] - a * mu;
    for (int n = threadIdx.x; n < N; n += blockDim.x) {
        int4 t = id[n];
        float p0 = Pr[t.x], p1 = Pr[t.y], p2 = Pr[t.z], p3 = Pr[t.w];
        float v = (a >= 0.f) ? fmaxf(fmaxf(p0, p1), fmaxf(p2, p3))
                             : fminf(fminf(p0, p1), fminf(p2, p3));
        v += Qr[n];
        float y = fmaf(a, v, c);
        st_v(&Or[n], y >= 0.f ? y : 0.2f * y);
    }
}

// ---------------------------------------------------------------------------
extern "C" void kernel_launch(void* const* d_in, const int* in_sizes, int n_in,
                              void* d_out, int out_size, void* d_ws, size_t ws_size,
                              hipStream_t stream)
{
    const float* coor   = (const float*)d_in[0];
    const float* f      = (const float*)d_in[1];
    const float* coor_q = (const float*)d_in[2];
    const float* f_q    = (const float*)d_in[3];
    const float* W1     = (const float*)d_in[4];
    const float* g1     = (const float*)d_in[5];
    const float* b1     = (const float*)d_in[6];
    const float* W2     = (const float*)d_in[7];
    const float* g2     = (const float*)d_in[8];
    const float* b2     = (const float*)d_in[9];
    float* out = (float*)d_out;

    char* ws = (char*)d_ws;
    size_t off = 0;
    auto alloc = [&](size_t bytes) { size_t o = off; off += (bytes + 255) & ~size_t(255); return o; };
    size_t o_idx1 = alloc((size_t)BATCH * NQ * 4 * 4);
    size_t o_idx2 = alloc((size_t)BATCH * NQ * 4 * 4);
    size_t o_W1a  = alloc((size_t)C1 * CIN * 2);
    size_t o_W1d  = alloc((size_t)C1 * CIN * 2);
    size_t o_Wstk = alloc((size_t)2 * C2 * C1 * 2);
    size_t o_fT   = alloc((size_t)BATCH * GCOARSE * CIN * 2);   // (B,G,C) bf16
    size_t o_fqT  = alloc((size_t)BATCH * NQ * CIN * 2);        // (B,N,C) bf16; reused for h_bf
    size_t o_P    = alloc((size_t)BATCH * C1 * GCOARSE * 4);
    size_t o_Q    = alloc((size_t)BATCH * C1 * NQ * 4);         // reused for hT
    size_t o_RS   = alloc((size_t)BATCH * 2 * C2 * NQ * 4);     // first 6MB reused for knn cand
    size_t o_stats = alloc(128);
    (void)ws_size;

    int* idx1 = (int*)(ws + o_idx1);
    int* idx2 = (int*)(ws + o_idx2);
    unsigned short* W1a  = (unsigned short*)(ws + o_W1a);
    unsigned short* W1d  = (unsigned short*)(ws + o_W1d);
    unsigned short* Wstk = (unsigned short*)(ws + o_Wstk);
    unsigned short* fT   = (unsigned short*)(ws + o_fT);
    unsigned short* fqT  = (unsigned short*)(ws + o_fqT);
    unsigned short* h_bf = (unsigned short*)(ws + o_fqT);       // alias
    float* P  = (float*)(ws + o_P);
    float* Q  = (float*)(ws + o_Q);
    unsigned short* hT = (unsigned short*)(ws + o_Q);           // alias
    float* RS = (float*)(ws + o_RS);
    float* cd2 = (float*)(ws + o_RS);
    int*   ci2 = (int*)(ws + o_RS + (size_t)2 * 1024 * 1024);
    float* cd1 = (float*)(ws + o_RS + (size_t)4 * 1024 * 1024);
    int*   ci1 = (int*)(ws + o_RS + (size_t)5 * 1024 * 1024);
    float* stats = (float*)(ws + o_stats);

    // 1. weights -> bf16
    prep_weights_bf<<<(C1 * CIN + 255) / 256, 256, 0, stream>>>(W1, W2, W1a, W1d, Wstk);

    // 2. activations -> transposed bf16 (N-major, K contiguous)
    transposeT_bf16<float><<<dim3(NQ / 32, CIN / 32, BATCH), dim3(32, 8), 0, stream>>>(f_q, fqT, CIN, NQ);
    transposeT_bf16<float><<<dim3(GCOARSE / 32, CIN / 32, BATCH), dim3(32, 8), 0, stream>>>(f, fT, CIN, GCOARSE);

    // 3. KNN split + merge (round-2 verbatim)
    knn_split<64><<<dim3(NQ / 256, 8, BATCH), 256, 0, stream>>>(coor_q, coor, cd1, ci1, NQ, GCOARSE, 8);
    knn_merge<8><<<(BATCH * NQ + 255) / 256, 256, 0, stream>>>(cd1, ci1, idx1, BATCH * NQ);
    knn_split<256><<<dim3(NQ / 256, 16, BATCH), 256, 0, stream>>>(coor_q, coor_q, cd2, ci2, NQ, NQ, 16);
    knn_merge<16><<<(BATCH * NQ + 255) / 256, 256, 0, stream>>>(cd2, ci2, idx2, BATCH * NQ);

    // 4. P = W1a @ f : (512x768)@(768x512), 64x64 tiles
    gemm_mfma<2, 2><<<dim3(GCOARSE / 64, C1 / 64, BATCH), 256, 0, stream>>>(
        W1a, 0, fT, (size_t)GCOARSE * CIN, P, (size_t)C1 * GCOARSE, GCOARSE, CIN);

    // 5. Q = W1d @ f_q : (512x768)@(768x4096), 128x128 tiles
    gemm_mfma<4, 4><<<dim3(NQ / 128, C1 / 128, BATCH), 256, 0, stream>>>(
        W1d, 0, fqT, (size_t)NQ * CIN, Q, (size_t)C1 * NQ, NQ, CIN);

    // 6. GN1 stats + apply -> h_bf
    hipMemsetAsync(stats, 0, 128, stream);
    stats_kernel<<<dim3(C1, BATCH), 256, 0, stream>>>(
        P, (size_t)C1 * GCOARSE, GCOARSE, Q, (size_t)C1 * NQ, idx1, stats, C1 / 4, NQ);
    apply_kernel<unsigned short><<<dim3(C1, BATCH), 256, 0, stream>>>(
        P, (size_t)C1 * GCOARSE, GCOARSE, Q, (size_t)C1 * NQ, idx1, stats, g1, b1,
        h_bf, (size_t)C1 * NQ, C1 / 4, NQ, 1.0f / ((float)(C1 / 4) * NQ * 4));

    // 7. hT = transpose(h_bf) -> (B,N,C1) bf16
    transposeT_bf16<unsigned short><<<dim3(NQ / 32, C1 / 32, BATCH), dim3(32, 8), 0, stream>>>(h_bf, hT, C1, NQ);

    // 8. [R;S] = Wstk @ h : (1536x512)@(512x4096), 128x128 tiles
    gemm_mfma<4, 4><<<dim3(NQ / 128, (2 * C2) / 128, BATCH), 256, 0, stream>>>(
        Wstk, 0, hT, (size_t)NQ * C1, RS, (size_t)2 * C2 * NQ, NQ, C1);

    // 9. GN2 stats + apply -> out (stats floats [16,32), disjoint from stage 1)
    stats_kernel<<<dim3(C2, BATCH), 256, 0, stream>>>(
        RS, (size_t)2 * C2 * NQ, NQ,
        RS + (size_t)C2 * NQ, (size_t)2 * C2 * NQ, idx2, stats + 16, C2 / 4, NQ);
    apply_kernel<float><<<dim3(C2, BATCH), 256, 0, stream>>>(
        RS, (size_t)2 * C2 * NQ, NQ,
        RS + (size_t)C2 * NQ, (size_t)2 * C2 * NQ, idx2, stats + 16, g2, b2,
        out, (size_t)C2 * NQ, C2 / 4, NQ, 1.0f / ((float)(C2 / 4) * NQ * 4));
}